// Round 18
// baseline (200.705 us; speedup 1.0000x reference)
//
#include <hip/hip_runtime.h>
#include <hip/hip_bf16.h>
#include <stdint.h>

#define S_LEN 2048
#define DM 1024
#define NH 16
#define HD 64

typedef __bf16 bf16x8 __attribute__((ext_vector_type(8)));
typedef float f32x4 __attribute__((ext_vector_type(4)));
typedef unsigned short u16x4 __attribute__((ext_vector_type(4)));

#if __has_builtin(__builtin_amdgcn_exp2f)
#define EXP2F(x) __builtin_amdgcn_exp2f(x)
#else
#define EXP2F(x) exp2f(x)
#endif

__device__ __forceinline__ unsigned short f2bf(float f){
  union { float f; uint32_t u; } v; v.f = f;
  uint32_t r = v.u + 0x7fffu + ((v.u >> 16) & 1u);
  return (unsigned short)(r >> 16);
}

__device__ __forceinline__ float bf2f(unsigned short u){
  union { uint32_t u; float f; } v; v.u = ((uint32_t)u) << 16;
  return v.f;
}

__device__ __forceinline__ void load_lds16(const void* g, void* l){
  __builtin_amdgcn_global_load_lds((const __attribute__((address_space(1))) void*)g,
                                   (__attribute__((address_space(3))) void*)l, 16, 0, 0);
}

__device__ __forceinline__ f32x4 mfma16(bf16x8 a, bf16x8 b, f32x4 c){
  return __builtin_amdgcn_mfma_f32_16x16x32_bf16(a, b, c, 0, 0, 0);
}

// rows are 64 bf16 = 128B; swizzle byte_off ^= ((row&7)<<4) to break the 128B-stride bank conflict
__device__ __forceinline__ bf16x8 lds_swz_read(const unsigned short* base, int row, int cb){
  int addr = (row << 7) + (cb ^ ((row & 7) << 4));
  return *reinterpret_cast<const bf16x8*>(reinterpret_cast<const char*>(base) + addr);
}

// ---------------- prep: f32 -> bf16 for x and the 4 weight matrices ----------------
__global__ void prep_kernel(const float* __restrict__ x,
                            const float* __restrict__ wq, const float* __restrict__ wk,
                            const float* __restrict__ wv, const float* __restrict__ wo,
                            unsigned short* __restrict__ ws_base){
  long idx = ((long)blockIdx.x * 256 + threadIdx.x) * 4;
  const float* s; unsigned short* d; long off;
  if (idx < (1L << 22)) { s = x; d = ws_base; off = idx; }
  else {
    long r = idx - (1L << 22);
    int wsel = (int)(r >> 20);
    off = r & ((1L << 20) - 1);
    s = wsel == 0 ? wq : wsel == 1 ? wk : wsel == 2 ? wv : wo;
    d = ws_base + (1L << 22) + ((long)wsel << 20);
  }
  float4 f = *reinterpret_cast<const float4*>(s + off);
  u16x4 o;
  o[0] = f2bf(f.x); o[1] = f2bf(f.y); o[2] = f2bf(f.z); o[3] = f2bf(f.w);
  *reinterpret_cast<u16x4*>(d + off) = o;
}

// ---------------- GEMM: C = A[M,1024] * B[N,1024]^T + bias ----------------
template<int MODE>
__global__ __launch_bounds__(256, 2)
void gemm_bt_kernel(const unsigned short* __restrict__ A,
                    const unsigned short* __restrict__ B0,
                    const unsigned short* __restrict__ B1,
                    const unsigned short* __restrict__ B2,
                    const float* __restrict__ bias0,
                    const float* __restrict__ bias1,
                    const float* __restrict__ bias2,
                    unsigned short* __restrict__ q_out,
                    unsigned short* __restrict__ k_out,
                    unsigned short* __restrict__ vt_out,
                    float* __restrict__ f_out)
{
  __shared__ unsigned short As[128 * 64];
  __shared__ unsigned short Bs[128 * 64];
  const int tid = threadIdx.x;
  const int lane = tid & 63;
  const int w = tid >> 6;
  const int wr = w >> 1, wc = w & 1;
  const int mBase = blockIdx.y * 128;
  int nb = blockIdx.x;
  const unsigned short* Bmat; const float* bias; int mat;
  if constexpr (MODE == 0) {
    mat = nb >> 3;
    nb &= 7;
    Bmat = mat == 0 ? B0 : (mat == 1 ? B1 : B2);
    bias = mat == 0 ? bias0 : (mat == 1 ? bias1 : bias2);
  } else { mat = 0; Bmat = B0; bias = bias0; }
  const int nBase = nb * 128;

  f32x4 acc[4][4] = {};
  const int srow = lane >> 3;
  const int ksrc = ((lane & 7) ^ srow) * 8;
  const unsigned short* ArowBase = A    + (size_t)(mBase + w * 32 + srow) * DM + ksrc;
  const unsigned short* BrowBase = Bmat + (size_t)(nBase + w * 32 + srow) * DM + ksrc;

  for (int kt = 0; kt < 16; ++kt) {
    #pragma unroll
    for (int i = 0; i < 4; ++i) {
      load_lds16(ArowBase + (size_t)(i * 8) * DM + kt * 64, &As[(w * 4 + i) * 512]);
      load_lds16(BrowBase + (size_t)(i * 8) * DM + kt * 64, &Bs[(w * 4 + i) * 512]);
    }
    __syncthreads();
    #pragma unroll
    for (int kk = 0; kk < 2; ++kk) {
      bf16x8 af[4], bfr[4];
      const int cb = kk * 64 + ((lane >> 4) << 4);
      #pragma unroll
      for (int m = 0; m < 4; ++m)
        af[m] = lds_swz_read(As, wr * 64 + m * 16 + (lane & 15), cb);
      #pragma unroll
      for (int n = 0; n < 4; ++n)
        bfr[n] = lds_swz_read(Bs, wc * 64 + n * 16 + (lane & 15), cb);
      #pragma unroll
      for (int m = 0; m < 4; ++m)
        #pragma unroll
        for (int n = 0; n < 4; ++n)
          acc[m][n] = mfma16(af[m], bfr[n], acc[m][n]);
    }
    __syncthreads();
  }

  #pragma unroll
  for (int m = 0; m < 4; ++m) {
    #pragma unroll
    for (int n = 0; n < 4; ++n) {
      const int col = nBase + wc * 64 + n * 16 + (lane & 15);
      const float bv = bias[col];
      const int row0 = mBase + wr * 64 + m * 16 + ((lane >> 4) << 2);
      if constexpr (MODE == 1) {
        #pragma unroll
        for (int j = 0; j < 4; ++j)
          f_out[(size_t)(row0 + j) * DM + col] = acc[m][n][j] + bv;
      } else {
        const int h = col >> 6, d = col & 63;
        if (mat < 2) {
          unsigned short* dst = (mat == 0) ? q_out : k_out;
          #pragma unroll
          for (int j = 0; j < 4; ++j) {
            const int row = row0 + j;
            const int b = row >> 11, s = row & 2047;
            dst[(((size_t)b * NH + h) * S_LEN + s) * HD + d] = f2bf(acc[m][n][j] + bv);
          }
        } else {
          const int b = row0 >> 11, s = row0 & 2047;
          u16x4 pk;
          #pragma unroll
          for (int j = 0; j < 4; ++j) pk[j] = f2bf(acc[m][n][j] + bv);
          *reinterpret_cast<u16x4*>(&vt_out[(((size_t)b * NH + h) * HD + d) * S_LEN + s]) = pk;
        }
      }
    }
  }
}

// ---------------- flash attention: 8-wave blocks + CONTIGUOUS bias loads ----------------
// r17 base (best: total 200us). Single change this round: waves_per_eu(4,5) -> (4,6).
// The kernel's true footprint is 64 arch + 16 acc = 80 unified regs -> HW admits
// floor(512/80) = 6 waves/EU, but max=5 capped residency. min stays 4 (128-reg
// allocation budget, proven no-spill); budget at max-target 512/6 = 85 >= 80.
// TRIPWIRES: VGPR_Count must stay 64, WRITE_SIZE ~35MB. If spill -> revert to (4,5).
// Schedule per tile (proven): entry raw(t)=8; BAR; stage(2); vmcnt(2) retires raw(t);
// COMBINE (fold+bf16+Ps roundtrip); issue raw(t+1)(8); vmcnt(8) retires stages; BAR;
// COMPUTE.

#define WAITV8 do { asm volatile("s_waitcnt vmcnt(8)" ::: "memory"); } while (0)
#define WAITV2 do { asm volatile("s_waitcnt vmcnt(2)" ::: "memory"); } while (0)
#define WAITV0 do { asm volatile("s_waitcnt vmcnt(0)" ::: "memory"); } while (0)
#define SB0    __builtin_amdgcn_sched_barrier(0)
#define BAR    __builtin_amdgcn_s_barrier()

// lB is LOCAL to this split (bpB/mpB include kv0 but NOT q); lB in [0, 448].
// Contiguity-transposed: instr i covers rows 4i..4i+3; 16 consecutive lanes read
// 256B contiguous within one row.
#define LOAD_RAW(lB) do {                                                              \
    rb0 = *reinterpret_cast<const f32x4*>(bpB + (size_t)(0  + rg) * S_LEN + (lB) + cl4); \
    rb1 = *reinterpret_cast<const f32x4*>(bpB + (size_t)(4  + rg) * S_LEN + (lB) + cl4); \
    rb2 = *reinterpret_cast<const f32x4*>(bpB + (size_t)(8  + rg) * S_LEN + (lB) + cl4); \
    rb3 = *reinterpret_cast<const f32x4*>(bpB + (size_t)(12 + rg) * S_LEN + (lB) + cl4); \
    rm0 = *reinterpret_cast<const f32x4*>(mpB + (size_t)(0  + rg) * S_LEN + (lB) + cl4); \
    rm1 = *reinterpret_cast<const f32x4*>(mpB + (size_t)(4  + rg) * S_LEN + (lB) + cl4); \
    rm2 = *reinterpret_cast<const f32x4*>(mpB + (size_t)(8  + rg) * S_LEN + (lB) + cl4); \
    rm3 = *reinterpret_cast<const f32x4*>(mpB + (size_t)(12 + rg) * S_LEN + (lB) + cl4); \
  } while (0)

// fold (bias+mask)*L2E in loaded layout, quantize bf16, redistribute via per-wave Ps
// (swizzled byte ^= ((row&7)<<4) -- same convention as lds_swz_read), read back as
// fragment-layout u16x4: bm[n] = rows q, cols n*16+4g..+3.
#define COMBINE do {                                                                   \
    f32x4 c0_ = (rb0 + rm0) * L2E; f32x4 c1_ = (rb1 + rm1) * L2E;                      \
    f32x4 c2_ = (rb2 + rm2) * L2E; f32x4 c3_ = (rb3 + rm3) * L2E;                      \
    u16x4 p0_, p1_, p2_, p3_;                                                          \
    p0_[0]=f2bf(c0_[0]); p0_[1]=f2bf(c0_[1]); p0_[2]=f2bf(c0_[2]); p0_[3]=f2bf(c0_[3]);\
    p1_[0]=f2bf(c1_[0]); p1_[1]=f2bf(c1_[1]); p1_[2]=f2bf(c1_[2]); p1_[3]=f2bf(c1_[3]);\
    p2_[0]=f2bf(c2_[0]); p2_[1]=f2bf(c2_[1]); p2_[2]=f2bf(c2_[2]); p2_[3]=f2bf(c2_[3]);\
    p3_[0]=f2bf(c3_[0]); p3_[1]=f2bf(c3_[1]); p3_[2]=f2bf(c3_[2]); p3_[3]=f2bf(c3_[3]);\
    char* Pb_ = reinterpret_cast<char*>(Pw_);                                          \
    *reinterpret_cast<u16x4*>(Pb_ + ((0  + rg) << 7) + (cl8 ^ ((0 + rg) << 4))) = p0_; \
    *reinterpret_cast<u16x4*>(Pb_ + ((4  + rg) << 7) + (cl8 ^ ((4 + rg) << 4))) = p1_; \
    *reinterpret_cast<u16x4*>(Pb_ + ((8  + rg) << 7) + (cl8 ^ ((0 + rg) << 4))) = p2_; \
    *reinterpret_cast<u16x4*>(Pb_ + ((12 + rg) << 7) + (cl8 ^ ((4 + rg) << 4))) = p3_; \
    bm0 = *reinterpret_cast<const u16x4*>(Pb_ + (q << 7) + ((0 * 32 + g * 8) ^ qx_));  \
    bm1 = *reinterpret_cast<const u16x4*>(Pb_ + (q << 7) + ((1 * 32 + g * 8) ^ qx_));  \
    bm2 = *reinterpret_cast<const u16x4*>(Pb_ + (q << 7) + ((2 * 32 + g * 8) ^ qx_));  \
    bm3 = *reinterpret_cast<const u16x4*>(Pb_ + (q << 7) + ((3 * 32 + g * 8) ^ qx_));  \
  } while (0)

// kvB is GLOBAL (Kp/Vp do not include kv0). Wave w stages chunk w (rows w*8..w*8+7).
#define STAGE_K(kvB) \
    load_lds16(Kp + (size_t)((kvB) + w * 8 + srow) * HD + ksrc, &Ks[w * 512])

#define STAGE_V(kvB) \
    load_lds16(Vp + (size_t)(w * 8 + srow) * S_LEN + (kvB) + ksrc, &Vs[w * 512])

#define BIAS_COL(SCN, BMN) do {                                               \
    SCN[0] = SCN[0] * SC + bf2f(BMN[0]);                                      \
    SCN[1] = SCN[1] * SC + bf2f(BMN[1]);                                      \
    SCN[2] = SCN[2] * SC + bf2f(BMN[2]);                                      \
    SCN[3] = SCN[3] * SC + bf2f(BMN[3]);                                      \
    mt_ = fmaxf(mt_, fmaxf(fmaxf(SCN[0], SCN[1]), fmaxf(SCN[2], SCN[3])));    \
  } while (0)

#define EXP_COL(SCN) do {                                                     \
    SCN[0] = EXP2F(SCN[0] - mn_); SCN[1] = EXP2F(SCN[1] - mn_);               \
    SCN[2] = EXP2F(SCN[2] - mn_); SCN[3] = EXP2F(SCN[3] - mn_);               \
  } while (0)

#define PWR_COL(NN, SCN) do {                                                 \
    u16x4 pk_;                                                                \
    pk_[0] = f2bf(SCN[0]); pk_[1] = f2bf(SCN[1]);                             \
    pk_[2] = f2bf(SCN[2]); pk_[3] = f2bf(SCN[3]);                             \
    const int colb_ = ((NN) * 16 + 4 * g) * 2;                                \
    *reinterpret_cast<u16x4*>(                                                \
        reinterpret_cast<char*>(Pw_) + (q << 7) + (colb_ ^ ((q & 7) << 4))) = pk_; \
  } while (0)

#define COMPUTE_TILE do {                                                     \
    f32x4 sc0_, sc1_, sc2_, sc3_;                                             \
    { bf16x8 a_ = lds_swz_read(Ks, 0 * 16 + q, cbq);                          \
      bf16x8 b_ = lds_swz_read(Ks, 0 * 16 + q, 64 + cbq);                     \
      f32x4 z_ = {}; z_ = mfma16(a_, qf0, z_); sc0_ = mfma16(b_, qf1, z_); }  \
    { bf16x8 a_ = lds_swz_read(Ks, 1 * 16 + q, cbq);                          \
      bf16x8 b_ = lds_swz_read(Ks, 1 * 16 + q, 64 + cbq);                     \
      f32x4 z_ = {}; z_ = mfma16(a_, qf0, z_); sc1_ = mfma16(b_, qf1, z_); }  \
    { bf16x8 a_ = lds_swz_read(Ks, 2 * 16 + q, cbq);                          \
      bf16x8 b_ = lds_swz_read(Ks, 2 * 16 + q, 64 + cbq);                     \
      f32x4 z_ = {}; z_ = mfma16(a_, qf0, z_); sc2_ = mfma16(b_, qf1, z_); }  \
    { bf16x8 a_ = lds_swz_read(Ks, 3 * 16 + q, cbq);                          \
      bf16x8 b_ = lds_swz_read(Ks, 3 * 16 + q, 64 + cbq);                     \
      f32x4 z_ = {}; z_ = mfma16(a_, qf0, z_); sc3_ = mfma16(b_, qf1, z_); }  \
    float mt_ = -3.0e38f;                                                     \
    BIAS_COL(sc0_, bm0); BIAS_COL(sc1_, bm1);                                 \
    BIAS_COL(sc2_, bm2); BIAS_COL(sc3_, bm3);                                 \
    mt_ = fmaxf(mt_, __shfl_xor(mt_, 16));                                    \
    mt_ = fmaxf(mt_, __shfl_xor(mt_, 32));                                    \
    const float mn_ = fmaxf(m_run, mt_);                                      \
    const float corr_ = EXP2F(m_run - mn_);                                   \
    m_run = mn_;                                                              \
    EXP_COL(sc0_); EXP_COL(sc1_); EXP_COL(sc2_); EXP_COL(sc3_);               \
    f32x4 ls4_ = sc0_ + sc1_ + sc2_ + sc3_;                                   \
    float ls_ = ls4_[0] + ls4_[1] + ls4_[2] + ls4_[3];                        \
    ls_ += __shfl_xor(ls_, 16);                                               \
    ls_ += __shfl_xor(ls_, 32);                                               \
    l_run = l_run * corr_ + ls_;                                              \
    acc0_ *= corr_; acc1_ *= corr_; acc2_ *= corr_; acc3_ *= corr_;           \
    PWR_COL(0, sc0_); PWR_COL(1, sc1_); PWR_COL(2, sc2_); PWR_COL(3, sc3_);   \
    bf16x8 pf0_ = lds_swz_read(Pw_, q, cbq);                                  \
    bf16x8 pf1_ = lds_swz_read(Pw_, q, 64 + cbq);                             \
    { bf16x8 a_ = lds_swz_read(Vs, 0 * 16 + q, cbq);                          \
      bf16x8 b_ = lds_swz_read(Vs, 0 * 16 + q, 64 + cbq);                     \
      acc0_ = mfma16(a_, pf0_, acc0_); acc0_ = mfma16(b_, pf1_, acc0_); }     \
    { bf16x8 a_ = lds_swz_read(Vs, 1 * 16 + q, cbq);                          \
      bf16x8 b_ = lds_swz_read(Vs, 1 * 16 + q, 64 + cbq);                     \
      acc1_ = mfma16(a_, pf0_, acc1_); acc1_ = mfma16(b_, pf1_, acc1_); }     \
    { bf16x8 a_ = lds_swz_read(Vs, 2 * 16 + q, cbq);                          \
      bf16x8 b_ = lds_swz_read(Vs, 2 * 16 + q, 64 + cbq);                     \
      acc2_ = mfma16(a_, pf0_, acc2_); acc2_ = mfma16(b_, pf1_, acc2_); }     \
    { bf16x8 a_ = lds_swz_read(Vs, 3 * 16 + q, cbq);                          \
      bf16x8 b_ = lds_swz_read(Vs, 3 * 16 + q, 64 + cbq);                     \
      acc3_ = mfma16(a_, pf0_, acc3_); acc3_ = mfma16(b_, pf1_, acc3_); }     \
  } while (0)

__global__ __launch_bounds__(512) __attribute__((amdgpu_waves_per_eu(4, 6)))
void attn_kernel(const unsigned short* __restrict__ Q,
                 const unsigned short* __restrict__ Kmat,
                 const unsigned short* __restrict__ Vt,
                 const float* __restrict__ rel_bias,
                 const float* __restrict__ mask,
                 unsigned short* __restrict__ ctxp0,
                 unsigned short* __restrict__ ctxp1,
                 unsigned short* __restrict__ ctxp2,
                 unsigned short* __restrict__ ctxp3,
                 float* __restrict__ Mbuf,
                 float* __restrict__ Lbuf)
{
  __shared__ unsigned short Ks[64 * 64];       // 8 KB, shared by all 8 waves
  __shared__ unsigned short Vs[64 * 64];       // 8 KB
  __shared__ unsigned short Ps[8][16 * 64];    // 16 KB, per-wave

  // XCD-chunked bijective remap: 2048 = 8 XCDs x 256; (s, b) fastest so the 8 blocks
  // sharing the same bias rows (4 splits x 2 batches) land on the same XCD.
  const int logical = (blockIdx.x & 7) * 256 + (blockIdx.x >> 3);
  const int s  = logical & 3;          // K-split (512 keys each)
  const int b  = (logical >> 2) & 1;
  const int qt = (logical >> 3) & 15;  // 128 q-rows per block
  const int h  = logical >> 7;

  const int lane = threadIdx.x & 63, w = threadIdx.x >> 6;  // w in 0..7
  const int q = lane & 15, g = lane >> 4;
  const int bh = b * NH + h;
  const int qRow = qt * 128 + w * 16;
  const int kv0 = s << 9;              // this split's k base (global elements)
  const unsigned short* Qp = Q + ((size_t)bh * S_LEN + qRow) * HD;
  bf16x8 qf0 = *reinterpret_cast<const bf16x8*>(Qp + (size_t)q * HD + g * 8);
  bf16x8 qf1 = *reinterpret_cast<const bf16x8*>(Qp + (size_t)q * HD + 32 + g * 8);

  const unsigned short* Kp = Kmat + (size_t)bh * S_LEN * HD;
  const unsigned short* Vp = Vt + (size_t)bh * HD * S_LEN;
  // base WITHOUT q: contiguity-transposed loads add their own row offsets
  const float* bpB = rel_bias + (size_t)h * S_LEN * S_LEN + (size_t)qRow * S_LEN + kv0;
  const float* mpB = mask + (size_t)qRow * S_LEN + kv0;

  float m_run = -3.0e38f, l_run = 0.f;
  f32x4 acc0_ = {}, acc1_ = {}, acc2_ = {}, acc3_ = {};
  f32x4 rb0, rb1, rb2, rb3, rm0, rm1, rm2, rm3;
  u16x4 bm0, bm1, bm2, bm3;

  const float SC  = 0.125f * 1.44269504089f;  // head scale * log2(e)
  const float L2E = 1.44269504089f;

  const int srow = lane >> 3;
  const int ksrc = ((lane & 7) ^ srow) * 8;   // pre-swizzled global k-offset
  const int cbq = g << 4;
  const int rg  = lane >> 4;                  // row-group for contiguous loads
  const int cl4 = (lane & 15) * 4;            // col offset (floats)
  const int cl8 = (lane & 15) * 8;            // col offset (bytes, bf16 LDS)
  const int qx_ = (q & 7) << 4;
  unsigned short* Pw_ = Ps[w];

  // prologue: raw(0) in flight (8) -- loop entry invariant
  LOAD_RAW(0);
  SB0;

  for (int t = 0; t < 7; ++t) {
    const int kvB = kv0 + t * 64;      // global
    BAR;                               // all waves done reading Ks/Vs/Ps of t-1
    STAGE_K(kvB); STAGE_V(kvB);        // 2 ops; in-flight: raw(t)8 + stage2
    SB0;
    WAITV2; SB0;                       // retire raw(t); stages remain
    COMBINE;                           // fold + bf16 + Ps roundtrip -> bm frags
    LOAD_RAW((t + 1) * 64);            // raw(t+1), LOCAL offset (max 448)
    SB0;
    WAITV8; SB0;                       // retire stages; raw(t+1) stays in flight
    BAR;                               // stages visible to all waves
    COMPUTE_TILE;
  }
  // tail t = 7
  {
    const int kvB = kv0 + 7 * 64;
    BAR;
    STAGE_K(kvB); STAGE_V(kvB);
    SB0;
    WAITV2; SB0;                       // retire raw(7)
    COMBINE;
    WAITV0; SB0;                       // drain stages
    BAR;
    COMPUTE_TILE;
  }

  // epilogue: normalize, redistribute through per-wave LDS, write split partial
  const float inv = 1.0f / l_run;
  acc0_ *= inv; acc1_ *= inv; acc2_ *= inv; acc3_ *= inv;
  PWR_COL(0, acc0_); PWR_COL(1, acc1_); PWR_COL(2, acc2_); PWR_COL(3, acc3_);
  bf16x8 c0 = lds_swz_read(Pw_, q, g << 4);
  bf16x8 c1 = lds_swz_read(Pw_, q, 64 + (g << 4));
  unsigned short* pbase = (s == 0) ? ctxp0 : (s == 1) ? ctxp1 : (s == 2) ? ctxp2 : ctxp3;
  unsigned short* cp = pbase + ((size_t)(b * S_LEN + qRow + q)) * DM + h * HD;
  *reinterpret_cast<bf16x8*>(cp + 8 * g) = c0;
  *reinterpret_cast<bf16x8*>(cp + 32 + 8 * g) = c1;
  if (g == 0) {
    const int mlIdx = (s << 16) + (bh << 11) + qRow + q;
    Mbuf[mlIdx] = m_run;
    Lbuf[mlIdx] = l_run;
  }
}

// ---------------- merge: combine the four K-split partials ----------------
__global__ void merge_kernel(const unsigned short* __restrict__ ctxp0,
                             const unsigned short* __restrict__ ctxp1,
                             const unsigned short* __restrict__ ctxp2,
                             const unsigned short* __restrict__ ctxp3,
                             const float* __restrict__ Mbuf,
                             const float* __restrict__ Lbuf,
                             unsigned short* __restrict__ ctx){
  const long e = ((long)blockIdx.x * 256 + threadIdx.x) * 4;  // elem in [B*S*DM = 4M]
  const int b = (int)(e >> 21);
  const int srow = (int)((e >> 10) & 2047);
  const int d = (int)(e & 1023);
  const int h = d >> 6;
  const int idx = ((b * NH + h) << 11) + srow;
  const float m0 = Mbuf[idx],               m1 = Mbuf[(1 << 16) + idx];
  const float m2 = Mbuf[(2 << 16) + idx],   m3 = Mbuf[(3 << 16) + idx];
  const float l0 = Lbuf[idx],               l1 = Lbuf[(1 << 16) + idx];
  const float l2 = Lbuf[(2 << 16) + idx],   l3 = Lbuf[(3 << 16) + idx];
  const float mm = fmaxf(fmaxf(m0, m1), fmaxf(m2, m3));
  const float w0 = EXP2F(m0 - mm) * l0;
  const float w1 = EXP2F(m1 - mm) * l1;
  const float w2 = EXP2F(m2 - mm) * l2;
  const float w3 = EXP2F(m3 - mm) * l3;
  const float inv = 1.0f / (w0 + w1 + w2 + w3);
  u16x4 c0 = *reinterpret_cast<const u16x4*>(ctxp0 + e);
  u16x4 c1 = *reinterpret_cast<const u16x4*>(ctxp1 + e);
  u16x4 c2 = *reinterpret_cast<const u16x4*>(ctxp2 + e);
  u16x4 c3 = *reinterpret_cast<const u16x4*>(ctxp3 + e);
  u16x4 o;
  #pragma unroll
  for (int j = 0; j < 4; ++j)
    o[j] = f2bf((bf2f(c0[j]) * w0 + bf2f(c1[j]) * w1 +
                 bf2f(c2[j]) * w2 + bf2f(c3[j]) * w3) * inv);
  *reinterpret_cast<u16x4*>(ctx + e) = o;
}

extern "C" void kernel_launch(void* const* d_in, const int* in_sizes, int n_in,
                              void* d_out, int out_size, void* d_ws, size_t ws_size,
                              hipStream_t stream) {
  (void)in_sizes; (void)n_in; (void)out_size; (void)ws_size;
  const float* x  = (const float*)d_in[0];
  const float* rb = (const float*)d_in[1];
  const float* mk = (const float*)d_in[2];
  const float* Wq = (const float*)d_in[3];
  const float* bq = (const float*)d_in[4];
  const float* Wk = (const float*)d_in[5];
  const float* bk = (const float*)d_in[6];
  const float* Wv = (const float*)d_in[7];
  const float* bv = (const float*)d_in[8];
  const float* Wo = (const float*)d_in[9];
  const float* bo = (const float*)d_in[10];
  float* out = (float*)d_out;

  // ws layout (unsigned short elems), 24M total = 48MB:
  //  [0,4M)    xb      (DEAD after gemm<0> -> split-1 partial)
  //  [4M,5M)   wqb     (DEAD after gemm<0> -> Mbuf/Lbuf)
  //  [5M,6M)   wkb     [6M,7M) wvb    [7M,8M) wob (live until gemm<1>)
  //  [8M,12M)  Qw   [12M,16M) Kw   [16M,20M) Vtw
  //  [20M,24M) ctx  (split-0 partial, then merged in place)
  // d_out (16MB f32) doubles as scratch for split-2/3 partials, overwritten by gemm<1>.
  unsigned short* ws  = (unsigned short*)d_ws;
  unsigned short* xb  = ws;
  unsigned short* wqb = ws + (1L << 22);
  unsigned short* wkb = wqb + (1L << 20);
  unsigned short* wvb = wkb + (1L << 20);
  unsigned short* wob = wvb + (1L << 20);
  unsigned short* Qw  = wob + (1L << 20);
  unsigned short* Kw  = Qw + (1L << 22);
  unsigned short* Vtw = Kw + (1L << 22);
  unsigned short* ctx = Vtw + (1L << 22);
  unsigned short* ctxp1 = xb;
  unsigned short* ctxp2 = (unsigned short*)d_out;
  unsigned short* ctxp3 = (unsigned short*)d_out + (1L << 22);
  float* Mb = (float*)wqb;
  float* Lb = (float*)(wqb + (1L << 19));

  prep_kernel<<<8192, 256, 0, stream>>>(x, Wq, Wk, Wv, Wo, ws);
  gemm_bt_kernel<0><<<dim3(24, 32), 256, 0, stream>>>(
      xb, wqb, wkb, wvb, bq, bk, bv, Qw, Kw, Vtw, nullptr);
  attn_kernel<<<2048, 512, 0, stream>>>(Qw, Kw, Vtw, rb, mk, ctx, ctxp1, ctxp2, ctxp3, Mb, Lb);
  merge_kernel<<<4096, 256, 0, stream>>>(ctx, ctxp1, ctxp2, ctxp3, Mb, Lb, ctx);
  gemm_bt_kernel<1><<<dim3(8, 32), 256, 0, stream>>>(
      ctx, wob, nullptr, nullptr, bo, nullptr, nullptr, nullptr, nullptr, nullptr, out);
}

// Round 19
// 197.534 us; speedup vs baseline: 1.0161x; 1.0161x over previous
//
#include <hip/hip_runtime.h>
#include <hip/hip_bf16.h>
#include <stdint.h>

#define S_LEN 2048
#define DM 1024
#define NH 16
#define HD 64

typedef __bf16 bf16x8 __attribute__((ext_vector_type(8)));
typedef float f32x4 __attribute__((ext_vector_type(4)));
typedef unsigned short u16x4 __attribute__((ext_vector_type(4)));

#if __has_builtin(__builtin_amdgcn_exp2f)
#define EXP2F(x) __builtin_amdgcn_exp2f(x)
#else
#define EXP2F(x) exp2f(x)
#endif

__device__ __forceinline__ unsigned short f2bf(float f){
  union { float f; uint32_t u; } v; v.f = f;
  uint32_t r = v.u + 0x7fffu + ((v.u >> 16) & 1u);
  return (unsigned short)(r >> 16);
}

__device__ __forceinline__ float bf2f(unsigned short u){
  union { uint32_t u; float f; } v; v.u = ((uint32_t)u) << 16;
  return v.f;
}

__device__ __forceinline__ void load_lds16(const void* g, void* l){
  __builtin_amdgcn_global_load_lds((const __attribute__((address_space(1))) void*)g,
                                   (__attribute__((address_space(3))) void*)l, 16, 0, 0);
}

__device__ __forceinline__ f32x4 mfma16(bf16x8 a, bf16x8 b, f32x4 c){
  return __builtin_amdgcn_mfma_f32_16x16x32_bf16(a, b, c, 0, 0, 0);
}

// rows are 64 bf16 = 128B; swizzle byte_off ^= ((row&7)<<4) to break the 128B-stride bank conflict
__device__ __forceinline__ bf16x8 lds_swz_read(const unsigned short* base, int row, int cb){
  int addr = (row << 7) + (cb ^ ((row & 7) << 4));
  return *reinterpret_cast<const bf16x8*>(reinterpret_cast<const char*>(base) + addr);
}

// ---------------- prep: f32 -> bf16 for x and the 4 weight matrices ----------------
__global__ void prep_kernel(const float* __restrict__ x,
                            const float* __restrict__ wq, const float* __restrict__ wk,
                            const float* __restrict__ wv, const float* __restrict__ wo,
                            unsigned short* __restrict__ ws_base){
  long idx = ((long)blockIdx.x * 256 + threadIdx.x) * 4;
  const float* s; unsigned short* d; long off;
  if (idx < (1L << 22)) { s = x; d = ws_base; off = idx; }
  else {
    long r = idx - (1L << 22);
    int wsel = (int)(r >> 20);
    off = r & ((1L << 20) - 1);
    s = wsel == 0 ? wq : wsel == 1 ? wk : wsel == 2 ? wv : wo;
    d = ws_base + (1L << 22) + ((long)wsel << 20);
  }
  float4 f = *reinterpret_cast<const float4*>(s + off);
  u16x4 o;
  o[0] = f2bf(f.x); o[1] = f2bf(f.y); o[2] = f2bf(f.z); o[3] = f2bf(f.w);
  *reinterpret_cast<u16x4*>(d + off) = o;
}

// ---------------- GEMM: C = A[M,1024] * B[N,1024]^T + bias ----------------
template<int MODE>
__global__ __launch_bounds__(256, 2)
void gemm_bt_kernel(const unsigned short* __restrict__ A,
                    const unsigned short* __restrict__ B0,
                    const unsigned short* __restrict__ B1,
                    const unsigned short* __restrict__ B2,
                    const float* __restrict__ bias0,
                    const float* __restrict__ bias1,
                    const float* __restrict__ bias2,
                    unsigned short* __restrict__ q_out,
                    unsigned short* __restrict__ k_out,
                    unsigned short* __restrict__ vt_out,
                    float* __restrict__ f_out)
{
  __shared__ unsigned short As[128 * 64];
  __shared__ unsigned short Bs[128 * 64];
  const int tid = threadIdx.x;
  const int lane = tid & 63;
  const int w = tid >> 6;
  const int wr = w >> 1, wc = w & 1;
  const int mBase = blockIdx.y * 128;
  int nb = blockIdx.x;
  const unsigned short* Bmat; const float* bias; int mat;
  if constexpr (MODE == 0) {
    mat = nb >> 3;
    nb &= 7;
    Bmat = mat == 0 ? B0 : (mat == 1 ? B1 : B2);
    bias = mat == 0 ? bias0 : (mat == 1 ? bias1 : bias2);
  } else { mat = 0; Bmat = B0; bias = bias0; }
  const int nBase = nb * 128;

  f32x4 acc[4][4] = {};
  const int srow = lane >> 3;
  const int ksrc = ((lane & 7) ^ srow) * 8;
  const unsigned short* ArowBase = A    + (size_t)(mBase + w * 32 + srow) * DM + ksrc;
  const unsigned short* BrowBase = Bmat + (size_t)(nBase + w * 32 + srow) * DM + ksrc;

  for (int kt = 0; kt < 16; ++kt) {
    #pragma unroll
    for (int i = 0; i < 4; ++i) {
      load_lds16(ArowBase + (size_t)(i * 8) * DM + kt * 64, &As[(w * 4 + i) * 512]);
      load_lds16(BrowBase + (size_t)(i * 8) * DM + kt * 64, &Bs[(w * 4 + i) * 512]);
    }
    __syncthreads();
    #pragma unroll
    for (int kk = 0; kk < 2; ++kk) {
      bf16x8 af[4], bfr[4];
      const int cb = kk * 64 + ((lane >> 4) << 4);
      #pragma unroll
      for (int m = 0; m < 4; ++m)
        af[m] = lds_swz_read(As, wr * 64 + m * 16 + (lane & 15), cb);
      #pragma unroll
      for (int n = 0; n < 4; ++n)
        bfr[n] = lds_swz_read(Bs, wc * 64 + n * 16 + (lane & 15), cb);
      #pragma unroll
      for (int m = 0; m < 4; ++m)
        #pragma unroll
        for (int n = 0; n < 4; ++n)
          acc[m][n] = mfma16(af[m], bfr[n], acc[m][n]);
    }
    __syncthreads();
  }

  #pragma unroll
  for (int m = 0; m < 4; ++m) {
    #pragma unroll
    for (int n = 0; n < 4; ++n) {
      const int col = nBase + wc * 64 + n * 16 + (lane & 15);
      const float bv = bias[col];
      const int row0 = mBase + wr * 64 + m * 16 + ((lane >> 4) << 2);
      if constexpr (MODE == 1) {
        #pragma unroll
        for (int j = 0; j < 4; ++j)
          f_out[(size_t)(row0 + j) * DM + col] = acc[m][n][j] + bv;
      } else {
        const int h = col >> 6, d = col & 63;
        if (mat < 2) {
          unsigned short* dst = (mat == 0) ? q_out : k_out;
          #pragma unroll
          for (int j = 0; j < 4; ++j) {
            const int row = row0 + j;
            const int b = row >> 11, s = row & 2047;
            dst[(((size_t)b * NH + h) * S_LEN + s) * HD + d] = f2bf(acc[m][n][j] + bv);
          }
        } else {
          const int b = row0 >> 11, s = row0 & 2047;
          u16x4 pk;
          #pragma unroll
          for (int j = 0; j < 4; ++j) pk[j] = f2bf(acc[m][n][j] + bv);
          *reinterpret_cast<u16x4*>(&vt_out[(((size_t)b * NH + h) * HD + d) * S_LEN + s]) = pk;
        }
      }
    }
  }
}

// ---------------- flash attention: 8-wave blocks + contiguous bias + K/V DOUBLE-BUFFER ----------------
// r17 base (best: 200us total). This round: double-buffer K/V (+16KB LDS -> 48KB).
// Occupancy unchanged (LDS cap floor(160/48)=3 blocks/CU == register cap 512/80->3),
// but: (a) stage(t+1) is issued BEFORE compute(t) into the idle buffer -> full tile of
// latency cover (was ~20 instructions -- the r14 exposed-stage diagnosis); (b) read/write
// buffers disjoint -> ONE barrier per tile (was 2). waves_per_eu back to proven (4,5).
// FIFO (stage=2, raw=2): prologue [stage0,raw0] -> vmcnt(2) retires stage0 -> BAR.
// iter t: issue stage(t+1)->buf[(t+1)&1]; vmcnt(2) retires raw(t); COMBINE; issue
// raw(t+1); COMPUTE(buf[t&1]); vmcnt(2) retires stage(t+1); BAR publishes it.
// Lifetimes: iter t+1 writes buf[t&1]? No -- it writes buf[(t+2)&1]=buf[t&1] only at
// iter t+1's stage, which is after iter t's end-BAR (all reads of buf[t&1] complete).

#define WAITV2 do { asm volatile("s_waitcnt vmcnt(2)" ::: "memory"); } while (0)
#define WAITV0 do { asm volatile("s_waitcnt vmcnt(0)" ::: "memory"); } while (0)
#define SB0    __builtin_amdgcn_sched_barrier(0)
#define BAR    __builtin_amdgcn_s_barrier()

// lB is LOCAL to this split (bpB/mpB include kv0 but NOT q); lB in [0, 448].
// Contiguity-transposed: instr i covers rows 4i..4i+3; 16 consecutive lanes read
// 256B contiguous within one row.
#define LOAD_RAW(lB) do {                                                              \
    rb0 = *reinterpret_cast<const f32x4*>(bpB + (size_t)(0  + rg) * S_LEN + (lB) + cl4); \
    rb1 = *reinterpret_cast<const f32x4*>(bpB + (size_t)(4  + rg) * S_LEN + (lB) + cl4); \
    rb2 = *reinterpret_cast<const f32x4*>(bpB + (size_t)(8  + rg) * S_LEN + (lB) + cl4); \
    rb3 = *reinterpret_cast<const f32x4*>(bpB + (size_t)(12 + rg) * S_LEN + (lB) + cl4); \
    rm0 = *reinterpret_cast<const f32x4*>(mpB + (size_t)(0  + rg) * S_LEN + (lB) + cl4); \
    rm1 = *reinterpret_cast<const f32x4*>(mpB + (size_t)(4  + rg) * S_LEN + (lB) + cl4); \
    rm2 = *reinterpret_cast<const f32x4*>(mpB + (size_t)(8  + rg) * S_LEN + (lB) + cl4); \
    rm3 = *reinterpret_cast<const f32x4*>(mpB + (size_t)(12 + rg) * S_LEN + (lB) + cl4); \
  } while (0)

// fold (bias+mask)*L2E in loaded layout, quantize bf16, redistribute via per-wave Ps
// (swizzled byte ^= ((row&7)<<4)), read back as fragment-layout u16x4.
#define COMBINE do {                                                                   \
    f32x4 c0_ = (rb0 + rm0) * L2E; f32x4 c1_ = (rb1 + rm1) * L2E;                      \
    f32x4 c2_ = (rb2 + rm2) * L2E; f32x4 c3_ = (rb3 + rm3) * L2E;                      \
    u16x4 p0_, p1_, p2_, p3_;                                                          \
    p0_[0]=f2bf(c0_[0]); p0_[1]=f2bf(c0_[1]); p0_[2]=f2bf(c0_[2]); p0_[3]=f2bf(c0_[3]);\
    p1_[0]=f2bf(c1_[0]); p1_[1]=f2bf(c1_[1]); p1_[2]=f2bf(c1_[2]); p1_[3]=f2bf(c1_[3]);\
    p2_[0]=f2bf(c2_[0]); p2_[1]=f2bf(c2_[1]); p2_[2]=f2bf(c2_[2]); p2_[3]=f2bf(c2_[3]);\
    p3_[0]=f2bf(c3_[0]); p3_[1]=f2bf(c3_[1]); p3_[2]=f2bf(c3_[2]); p3_[3]=f2bf(c3_[3]);\
    char* Pb_ = reinterpret_cast<char*>(Pw_);                                          \
    *reinterpret_cast<u16x4*>(Pb_ + ((0  + rg) << 7) + (cl8 ^ ((0 + rg) << 4))) = p0_; \
    *reinterpret_cast<u16x4*>(Pb_ + ((4  + rg) << 7) + (cl8 ^ ((4 + rg) << 4))) = p1_; \
    *reinterpret_cast<u16x4*>(Pb_ + ((8  + rg) << 7) + (cl8 ^ ((0 + rg) << 4))) = p2_; \
    *reinterpret_cast<u16x4*>(Pb_ + ((12 + rg) << 7) + (cl8 ^ ((4 + rg) << 4))) = p3_; \
    bm0 = *reinterpret_cast<const u16x4*>(Pb_ + (q << 7) + ((0 * 32 + g * 8) ^ qx_));  \
    bm1 = *reinterpret_cast<const u16x4*>(Pb_ + (q << 7) + ((1 * 32 + g * 8) ^ qx_));  \
    bm2 = *reinterpret_cast<const u16x4*>(Pb_ + (q << 7) + ((2 * 32 + g * 8) ^ qx_));  \
    bm3 = *reinterpret_cast<const u16x4*>(Pb_ + (q << 7) + ((3 * 32 + g * 8) ^ qx_));  \
  } while (0)

// kvB is GLOBAL (Kp/Vp do not include kv0). Wave w stages chunk w (rows w*8..w*8+7).
#define STAGE_K(kvB, buf) \
    load_lds16(Kp + (size_t)((kvB) + w * 8 + srow) * HD + ksrc, &Ks[buf][w * 512])

#define STAGE_V(kvB, buf) \
    load_lds16(Vp + (size_t)(w * 8 + srow) * S_LEN + (kvB) + ksrc, &Vs[buf][w * 512])

#define BIAS_COL(SCN, BMN) do {                                               \
    SCN[0] = SCN[0] * SC + bf2f(BMN[0]);                                      \
    SCN[1] = SCN[1] * SC + bf2f(BMN[1]);                                      \
    SCN[2] = SCN[2] * SC + bf2f(BMN[2]);                                      \
    SCN[3] = SCN[3] * SC + bf2f(BMN[3]);                                      \
    mt_ = fmaxf(mt_, fmaxf(fmaxf(SCN[0], SCN[1]), fmaxf(SCN[2], SCN[3])));    \
  } while (0)

#define EXP_COL(SCN) do {                                                     \
    SCN[0] = EXP2F(SCN[0] - mn_); SCN[1] = EXP2F(SCN[1] - mn_);               \
    SCN[2] = EXP2F(SCN[2] - mn_); SCN[3] = EXP2F(SCN[3] - mn_);               \
  } while (0)

#define PWR_COL(NN, SCN) do {                                                 \
    u16x4 pk_;                                                                \
    pk_[0] = f2bf(SCN[0]); pk_[1] = f2bf(SCN[1]);                             \
    pk_[2] = f2bf(SCN[2]); pk_[3] = f2bf(SCN[3]);                             \
    const int colb_ = ((NN) * 16 + 4 * g) * 2;                                \
    *reinterpret_cast<u16x4*>(                                                \
        reinterpret_cast<char*>(Pw_) + (q << 7) + (colb_ ^ ((q & 7) << 4))) = pk_; \
  } while (0)

#define COMPUTE_TILE(KSB, VSB) do {                                           \
    const unsigned short* KSB_ = (KSB);                                       \
    const unsigned short* VSB_ = (VSB);                                       \
    f32x4 sc0_, sc1_, sc2_, sc3_;                                             \
    { bf16x8 a_ = lds_swz_read(KSB_, 0 * 16 + q, cbq);                        \
      bf16x8 b_ = lds_swz_read(KSB_, 0 * 16 + q, 64 + cbq);                   \
      f32x4 z_ = {}; z_ = mfma16(a_, qf0, z_); sc0_ = mfma16(b_, qf1, z_); }  \
    { bf16x8 a_ = lds_swz_read(KSB_, 1 * 16 + q, cbq);                        \
      bf16x8 b_ = lds_swz_read(KSB_, 1 * 16 + q, 64 + cbq);                   \
      f32x4 z_ = {}; z_ = mfma16(a_, qf0, z_); sc1_ = mfma16(b_, qf1, z_); }  \
    { bf16x8 a_ = lds_swz_read(KSB_, 2 * 16 + q, cbq);                        \
      bf16x8 b_ = lds_swz_read(KSB_, 2 * 16 + q, 64 + cbq);                   \
      f32x4 z_ = {}; z_ = mfma16(a_, qf0, z_); sc2_ = mfma16(b_, qf1, z_); }  \
    { bf16x8 a_ = lds_swz_read(KSB_, 3 * 16 + q, cbq);                        \
      bf16x8 b_ = lds_swz_read(KSB_, 3 * 16 + q, 64 + cbq);                   \
      f32x4 z_ = {}; z_ = mfma16(a_, qf0, z_); sc3_ = mfma16(b_, qf1, z_); }  \
    float mt_ = -3.0e38f;                                                     \
    BIAS_COL(sc0_, bm0); BIAS_COL(sc1_, bm1);                                 \
    BIAS_COL(sc2_, bm2); BIAS_COL(sc3_, bm3);                                 \
    mt_ = fmaxf(mt_, __shfl_xor(mt_, 16));                                    \
    mt_ = fmaxf(mt_, __shfl_xor(mt_, 32));                                    \
    const float mn_ = fmaxf(m_run, mt_);                                      \
    const float corr_ = EXP2F(m_run - mn_);                                   \
    m_run = mn_;                                                              \
    EXP_COL(sc0_); EXP_COL(sc1_); EXP_COL(sc2_); EXP_COL(sc3_);               \
    f32x4 ls4_ = sc0_ + sc1_ + sc2_ + sc3_;                                   \
    float ls_ = ls4_[0] + ls4_[1] + ls4_[2] + ls4_[3];                        \
    ls_ += __shfl_xor(ls_, 16);                                               \
    ls_ += __shfl_xor(ls_, 32);                                               \
    l_run = l_run * corr_ + ls_;                                              \
    acc0_ *= corr_; acc1_ *= corr_; acc2_ *= corr_; acc3_ *= corr_;           \
    PWR_COL(0, sc0_); PWR_COL(1, sc1_); PWR_COL(2, sc2_); PWR_COL(3, sc3_);   \
    bf16x8 pf0_ = lds_swz_read(Pw_, q, cbq);                                  \
    bf16x8 pf1_ = lds_swz_read(Pw_, q, 64 + cbq);                             \
    { bf16x8 a_ = lds_swz_read(VSB_, 0 * 16 + q, cbq);                        \
      bf16x8 b_ = lds_swz_read(VSB_, 0 * 16 + q, 64 + cbq);                   \
      acc0_ = mfma16(a_, pf0_, acc0_); acc0_ = mfma16(b_, pf1_, acc0_); }     \
    { bf16x8 a_ = lds_swz_read(VSB_, 1 * 16 + q, cbq);                        \
      bf16x8 b_ = lds_swz_read(VSB_, 1 * 16 + q, 64 + cbq);                   \
      acc1_ = mfma16(a_, pf0_, acc1_); acc1_ = mfma16(b_, pf1_, acc1_); }     \
    { bf16x8 a_ = lds_swz_read(VSB_, 2 * 16 + q, cbq);                        \
      bf16x8 b_ = lds_swz_read(VSB_, 2 * 16 + q, 64 + cbq);                   \
      acc2_ = mfma16(a_, pf0_, acc2_); acc2_ = mfma16(b_, pf1_, acc2_); }     \
    { bf16x8 a_ = lds_swz_read(VSB_, 3 * 16 + q, cbq);                        \
      bf16x8 b_ = lds_swz_read(VSB_, 3 * 16 + q, 64 + cbq);                   \
      acc3_ = mfma16(a_, pf0_, acc3_); acc3_ = mfma16(b_, pf1_, acc3_); }     \
  } while (0)

__global__ __launch_bounds__(512) __attribute__((amdgpu_waves_per_eu(4, 5)))
void attn_kernel(const unsigned short* __restrict__ Q,
                 const unsigned short* __restrict__ Kmat,
                 const unsigned short* __restrict__ Vt,
                 const float* __restrict__ rel_bias,
                 const float* __restrict__ mask,
                 unsigned short* __restrict__ ctxp0,
                 unsigned short* __restrict__ ctxp1,
                 unsigned short* __restrict__ ctxp2,
                 unsigned short* __restrict__ ctxp3,
                 float* __restrict__ Mbuf,
                 float* __restrict__ Lbuf)
{
  __shared__ unsigned short Ks[2][64 * 64];    // 16 KB, double-buffered, shared by 8 waves
  __shared__ unsigned short Vs[2][64 * 64];    // 16 KB
  __shared__ unsigned short Ps[8][16 * 64];    // 16 KB, per-wave

  // XCD-chunked bijective remap: 2048 = 8 XCDs x 256; (s, b) fastest so the 8 blocks
  // sharing the same bias rows (4 splits x 2 batches) land on the same XCD.
  const int logical = (blockIdx.x & 7) * 256 + (blockIdx.x >> 3);
  const int s  = logical & 3;          // K-split (512 keys each)
  const int b  = (logical >> 2) & 1;
  const int qt = (logical >> 3) & 15;  // 128 q-rows per block
  const int h  = logical >> 7;

  const int lane = threadIdx.x & 63, w = threadIdx.x >> 6;  // w in 0..7
  const int q = lane & 15, g = lane >> 4;
  const int bh = b * NH + h;
  const int qRow = qt * 128 + w * 16;
  const int kv0 = s << 9;              // this split's k base (global elements)
  const unsigned short* Qp = Q + ((size_t)bh * S_LEN + qRow) * HD;
  bf16x8 qf0 = *reinterpret_cast<const bf16x8*>(Qp + (size_t)q * HD + g * 8);
  bf16x8 qf1 = *reinterpret_cast<const bf16x8*>(Qp + (size_t)q * HD + 32 + g * 8);

  const unsigned short* Kp = Kmat + (size_t)bh * S_LEN * HD;
  const unsigned short* Vp = Vt + (size_t)bh * HD * S_LEN;
  // base WITHOUT q: contiguity-transposed loads add their own row offsets
  const float* bpB = rel_bias + (size_t)h * S_LEN * S_LEN + (size_t)qRow * S_LEN + kv0;
  const float* mpB = mask + (size_t)qRow * S_LEN + kv0;

  float m_run = -3.0e38f, l_run = 0.f;
  f32x4 acc0_ = {}, acc1_ = {}, acc2_ = {}, acc3_ = {};
  f32x4 rb0, rb1, rb2, rb3, rm0, rm1, rm2, rm3;
  u16x4 bm0, bm1, bm2, bm3;

  const float SC  = 0.125f * 1.44269504089f;  // head scale * log2(e)
  const float L2E = 1.44269504089f;

  const int srow = lane >> 3;
  const int ksrc = ((lane & 7) ^ srow) * 8;   // pre-swizzled global k-offset
  const int cbq = g << 4;
  const int rg  = lane >> 4;                  // row-group for contiguous loads
  const int cl4 = (lane & 15) * 4;            // col offset (floats)
  const int cl8 = (lane & 15) * 8;            // col offset (bytes, bf16 LDS)
  const int qx_ = (q & 7) << 4;
  unsigned short* Pw_ = Ps[w];

  // prologue: stage(0)->buf0 then raw(0); vmcnt(2) retires stage(0); BAR publishes.
  // Loop-top invariant: stage(t) published, raw(t) 2 in flight.
  STAGE_K(kv0, 0); STAGE_V(kv0, 0);
  SB0;
  LOAD_RAW(0);
  SB0;
  WAITV2; SB0;
  BAR;

  for (int t = 0; t < 8; ++t) {
    if (t < 7) {                       // stage(t+1) into idle buffer: full tile of cover
      const int kvB = kv0 + (t + 1) * 64;
      STAGE_K(kvB, (t + 1) & 1); STAGE_V(kvB, (t + 1) & 1);
      SB0;
      WAITV2; SB0;                     // retires raw(t); stage(t+1) stays in flight
    } else {
      WAITV0; SB0;                     // only raw(7) in queue
    }
    COMBINE;                           // fold + bf16 + Ps roundtrip -> bm frags
    if (t < 7) { LOAD_RAW((t + 1) * 64); SB0; }
    COMPUTE_TILE(Ks[t & 1], Vs[t & 1]);
    if (t < 7) {
      WAITV2; SB0;                     // retires stage(t+1); raw(t+1) stays in flight
      BAR;                             // publish stage(t+1); buf[t&1] reads all done
    }
  }

  // epilogue: normalize, redistribute through per-wave LDS, write split partial
  const float inv = 1.0f / l_run;
  acc0_ *= inv; acc1_ *= inv; acc2_ *= inv; acc3_ *= inv;
  PWR_COL(0, acc0_); PWR_COL(1, acc1_); PWR_COL(2, acc2_); PWR_COL(3, acc3_);
  bf16x8 c0 = lds_swz_read(Pw_, q, g << 4);
  bf16x8 c1 = lds_swz_read(Pw_, q, 64 + (g << 4));
  unsigned short* pbase = (s == 0) ? ctxp0 : (s == 1) ? ctxp1 : (s == 2) ? ctxp2 : ctxp3;
  unsigned short* cp = pbase + ((size_t)(b * S_LEN + qRow + q)) * DM + h * HD;
  *reinterpret_cast<bf16x8*>(cp + 8 * g) = c0;
  *reinterpret_cast<bf16x8*>(cp + 32 + 8 * g) = c1;
  if (g == 0) {
    const int mlIdx = (s << 16) + (bh << 11) + qRow + q;
    Mbuf[mlIdx] = m_run;
    Lbuf[mlIdx] = l_run;
  }
}

// ---------------- merge: combine the four K-split partials ----------------
__global__ void merge_kernel(const unsigned short* __restrict__ ctxp0,
                             const unsigned short* __restrict__ ctxp1,
                             const unsigned short* __restrict__ ctxp2,
                             const unsigned short* __restrict__ ctxp3,
                             const float* __restrict__ Mbuf,
                             const float* __restrict__ Lbuf,
                             unsigned short* __restrict__ ctx){
  const long e = ((long)blockIdx.x * 256 + threadIdx.x) * 4;  // elem in [B*S*DM = 4M]
  const int b = (int)(e >> 21);
  const int srow = (int)((e >> 10) & 2047);
  const int d = (int)(e & 1023);
  const int h = d >> 6;
  const int idx = ((b * NH + h) << 11) + srow;
  const float m0 = Mbuf[idx],               m1 = Mbuf[(1 << 16) + idx];
  const float m2 = Mbuf[(2 << 16) + idx],   m3 = Mbuf[(3 << 16) + idx];
  const float l0 = Lbuf[idx],               l1 = Lbuf[(1 << 16) + idx];
  const float l2 = Lbuf[(2 << 16) + idx],   l3 = Lbuf[(3 << 16) + idx];
  const float mm = fmaxf(fmaxf(m0, m1), fmaxf(m2, m3));
  const float w0 = EXP2F(m0 - mm) * l0;
  const float w1 = EXP2F(m1 - mm) * l1;
  const float w2 = EXP2F(m2 - mm) * l2;
  const float w3 = EXP2F(m3 - mm) * l3;
  const float inv = 1.0f / (w0 + w1 + w2 + w3);
  u16x4 c0 = *reinterpret_cast<const u16x4*>(ctxp0 + e);
  u16x4 c1 = *reinterpret_cast<const u16x4*>(ctxp1 + e);
  u16x4 c2 = *reinterpret_cast<const u16x4*>(ctxp2 + e);
  u16x4 c3 = *reinterpret_cast<const u16x4*>(ctxp3 + e);
  u16x4 o;
  #pragma unroll
  for (int j = 0; j < 4; ++j)
    o[j] = f2bf((bf2f(c0[j]) * w0 + bf2f(c1[j]) * w1 +
                 bf2f(c2[j]) * w2 + bf2f(c3[j]) * w3) * inv);
  *reinterpret_cast<u16x4*>(ctx + e) = o;
}

extern "C" void kernel_launch(void* const* d_in, const int* in_sizes, int n_in,
                              void* d_out, int out_size, void* d_ws, size_t ws_size,
                              hipStream_t stream) {
  (void)in_sizes; (void)n_in; (void)out_size; (void)ws_size;
  const float* x  = (const float*)d_in[0];
  const float* rb = (const float*)d_in[1];
  const float* mk = (const float*)d_in[2];
  const float* Wq = (const float*)d_in[3];
  const float* bq = (const float*)d_in[4];
  const float* Wk = (const float*)d_in[5];
  const float* bk = (const float*)d_in[6];
  const float* Wv = (const float*)d_in[7];
  const float* bv = (const float*)d_in[8];
  const float* Wo = (const float*)d_in[9];
  const float* bo = (const float*)d_in[10];
  float* out = (float*)d_out;

  // ws layout (unsigned short elems), 24M total = 48MB:
  //  [0,4M)    xb      (DEAD after gemm<0> -> split-1 partial)
  //  [4M,5M)   wqb     (DEAD after gemm<0> -> Mbuf/Lbuf)
  //  [5M,6M)   wkb     [6M,7M) wvb    [7M,8M) wob (live until gemm<1>)
  //  [8M,12M)  Qw   [12M,16M) Kw   [16M,20M) Vtw
  //  [20M,24M) ctx  (split-0 partial, then merged in place)
  // d_out (16MB f32) doubles as scratch for split-2/3 partials, overwritten by gemm<1>.
  unsigned short* ws  = (unsigned short*)d_ws;
  unsigned short* xb  = ws;
  unsigned short* wqb = ws + (1L << 22);
  unsigned short* wkb = wqb + (1L << 20);
  unsigned short* wvb = wkb + (1L << 20);
  unsigned short* wob = wvb + (1L << 20);
  unsigned short* Qw  = wob + (1L << 20);
  unsigned short* Kw  = Qw + (1L << 22);
  unsigned short* Vtw = Kw + (1L << 22);
  unsigned short* ctx = Vtw + (1L << 22);
  unsigned short* ctxp1 = xb;
  unsigned short* ctxp2 = (unsigned short*)d_out;
  unsigned short* ctxp3 = (unsigned short*)d_out + (1L << 22);
  float* Mb = (float*)wqb;
  float* Lb = (float*)(wqb + (1L << 19));

  prep_kernel<<<8192, 256, 0, stream>>>(x, Wq, Wk, Wv, Wo, ws);
  gemm_bt_kernel<0><<<dim3(24, 32), 256, 0, stream>>>(
      xb, wqb, wkb, wvb, bq, bk, bv, Qw, Kw, Vtw, nullptr);
  attn_kernel<<<2048, 512, 0, stream>>>(Qw, Kw, Vtw, rb, mk, ctx, ctxp1, ctxp2, ctxp3, Mb, Lb);
  merge_kernel<<<4096, 256, 0, stream>>>(ctx, ctxp1, ctxp2, ctxp3, Mb, Lb, ctx);
  gemm_bt_kernel<1><<<dim3(8, 32), 256, 0, stream>>>(
      ctx, wob, nullptr, nullptr, bo, nullptr, nullptr, nullptr, nullptr, nullptr, out);
}